// Round 2
// baseline (925.614 us; speedup 1.0000x reference)
//
#include <hip/hip_runtime.h>
#include <cstdint>
#include <cstddef>

// Problem constants
#define NB    4
#define SEQ   4096
#define EDIM  1024
#define DHEAD 512
#define NTOK  (NB * SEQ)     // 16384
#define FQKV  2560           // 2D + 2D + D = 1024+1024+512

typedef __bf16 bf16x8 __attribute__((ext_vector_type(8)));
typedef float  f32x4  __attribute__((ext_vector_type(4)));

__device__ __forceinline__ unsigned short f2bf(float f) {
  union { float f; unsigned int u; } v; v.f = f;
  return (unsigned short)((v.u + 0x7fffu + ((v.u >> 16) & 1u)) >> 16);
}
__device__ __forceinline__ float bf2f(unsigned short h) {
  union { unsigned int u; float f; } v; v.u = ((unsigned int)h) << 16;
  return v.f;
}

// async global->LDS, 16B per lane. LDS dest is wave-uniform base; HW puts
// lane i's 16B at base + i*16.
__device__ __forceinline__ void gld_lds16(const void* g, void* l) {
  __builtin_amdgcn_global_load_lds(
      (const __attribute__((address_space(1))) unsigned int*)g,
      (__attribute__((address_space(3))) unsigned int*)l, 16, 0, 0);
}

// ---------------------------------------------------------------------------
// m97-style GEMM-BT core: C(128x128) = A(128xK) * B(128xK)^T, bf16 in, fp32 acc.
// A: rows m0..m0+127 of an MxK row-major (lda). B: rows n0..n0+127 (ldb).
// 256 threads = 4 waves 2x2; each wave owns 64x64 = 4x4 MFMA 16x16 tiles.
// Epilogue epi(acc, wr, wc, lane): C[m][n], n = n0+wc*64+tn*16+(lane&15),
// m = m0+wr*64+tm*16+(lane>>4)*4+i.
// ---------------------------------------------------------------------------
template <class Epi>
__device__ __forceinline__ void gemm_bt_core(
    const unsigned short* __restrict__ A, const unsigned short* __restrict__ B,
    int K, int lda, int ldb, int m0, int n0, Epi epi) {
  __shared__ __align__(16) unsigned short As[128 * 32];
  __shared__ __align__(16) unsigned short Bs[128 * 32];
  const int t = threadIdx.x;
  const int w = t >> 6;
  const int lane = t & 63;
  const int wr = w >> 1, wc = w & 1;

  f32x4 acc[4][4];
#pragma unroll
  for (int i = 0; i < 4; ++i)
#pragma unroll
    for (int j = 0; j < 4; ++j) acc[i][j] = f32x4{0.f, 0.f, 0.f, 0.f};

  // Staging: tile = 128x32 bf16 = 8KB = 512 chunks of 16B. Chunk c: row=c>>2,
  // col8=(c&3)*8. Wave w covers chunks [w*128, w*128+128) via 2 gld16.
  const int c0 = (w * 2) * 64 + lane;
  const int c1 = (w * 2 + 1) * 64 + lane;
  const int r0 = c0 >> 2, col0 = (c0 & 3) * 8;
  const int r1 = c1 >> 2, col1 = (c1 & 3) * 8;
  unsigned short* ldsA0 = &As[(w * 2) * 512];       // wave-uniform
  unsigned short* ldsA1 = &As[(w * 2 + 1) * 512];
  unsigned short* ldsB0 = &Bs[(w * 2) * 512];
  unsigned short* ldsB1 = &Bs[(w * 2 + 1) * 512];
  const unsigned short* gA0 = A + (size_t)(m0 + r0) * lda + col0;
  const unsigned short* gA1 = A + (size_t)(m0 + r1) * lda + col1;
  const unsigned short* gB0 = B + (size_t)(n0 + r0) * ldb + col0;
  const unsigned short* gB1 = B + (size_t)(n0 + r1) * ldb + col1;

  for (int kt = 0; kt < K; kt += 32) {
    gld_lds16(gA0 + kt, ldsA0);
    gld_lds16(gA1 + kt, ldsA1);
    gld_lds16(gB0 + kt, ldsB0);
    gld_lds16(gB1 + kt, ldsB1);
    __syncthreads();  // compiler drains vmcnt before barrier -> staging visible

    bf16x8 af[4], bfr[4];
#pragma unroll
    for (int tm = 0; tm < 4; ++tm) {
      int r = wr * 64 + tm * 16 + (lane & 15);
      af[tm] = *(const bf16x8*)&As[r * 32 + (lane >> 4) * 8];
    }
#pragma unroll
    for (int tn = 0; tn < 4; ++tn) {
      int r = wc * 64 + tn * 16 + (lane & 15);
      bfr[tn] = *(const bf16x8*)&Bs[r * 32 + (lane >> 4) * 8];
    }
#pragma unroll
    for (int tm = 0; tm < 4; ++tm)
#pragma unroll
      for (int tn = 0; tn < 4; ++tn)
        acc[tm][tn] = __builtin_amdgcn_mfma_f32_16x16x32_bf16(
            af[tm], bfr[tn], acc[tm][tn], 0, 0, 0);
    __syncthreads();
  }
  epi(acc, wr, wc, lane);
}

// ---------------------------------------------------------------------------
// Small utility kernels
// ---------------------------------------------------------------------------
__global__ void k_cvt_x(const float* __restrict__ X, unsigned short* __restrict__ Xb) {
  int i = blockIdx.x * blockDim.x + threadIdx.x;  // per float4, exact grid
  float4 v = ((const float4*)X)[i];
  ushort4 o;
  o.x = f2bf(v.x); o.y = f2bf(v.y); o.z = f2bf(v.z); o.w = f2bf(v.w);
  ((ushort4*)Xb)[i] = o;
}

__global__ void k_pack_w(const float* __restrict__ Wq, const float* __restrict__ Wk,
                         const float* __restrict__ Wv, unsigned short* __restrict__ Wb) {
  int i = blockIdx.x * blockDim.x + threadIdx.x;  // per 4 elems, 2560*1024/4 total
  int idx = i * 4;
  int f = idx >> 10, e = idx & 1023;
  const float* src = (f < 1024) ? (Wq + (size_t)f * 1024)
                   : (f < 2048) ? (Wk + (size_t)(f - 1024) * 1024)
                                : (Wv + (size_t)(f - 2048) * 1024);
  float4 v = *(const float4*)(src + e);
  ushort4 o;
  o.x = f2bf(v.x); o.y = f2bf(v.y); o.z = f2bf(v.z); o.w = f2bf(v.w);
  ((ushort4*)Wb)[i] = o;
}

__global__ void k_pack_b(const float* __restrict__ bq, const float* __restrict__ bk,
                         const float* __restrict__ bv, float* __restrict__ bc) {
  int f = blockIdx.x * blockDim.x + threadIdx.x;  // 2560 total
  if (f < FQKV)
    bc[f] = (f < 1024) ? bq[f] : (f < 2048) ? bk[f - 1024] : bv[f - 2048];
}

__global__ void k_zero_f(float* __restrict__ p) {
  int i = blockIdx.x * blockDim.x + threadIdx.x;
  p[i] = 0.f;
}

// Vt[b][d][s] = QKV[b*SEQ+s][2048+d]  (bf16), tiled 32x32 transpose
__global__ void k_trv(const unsigned short* __restrict__ QKV, unsigned short* __restrict__ Vt) {
  __shared__ unsigned short tile[32][33];
  int s0 = blockIdx.x * 32, d0 = blockIdx.y * 32, b = blockIdx.z;
  int tx = threadIdx.x, ty = threadIdx.y;
#pragma unroll
  for (int j = 0; j < 4; ++j) {
    int s = s0 + ty * 4 + j;
    tile[ty * 4 + j][tx] = QKV[(size_t)(b * SEQ + s) * FQKV + 2048 + d0 + tx];
  }
  __syncthreads();
#pragma unroll
  for (int j = 0; j < 4; ++j) {
    int d = d0 + ty * 4 + j;
    Vt[(size_t)(b * DHEAD + d) * SEQ + s0 + tx] = tile[tx][ty * 4 + j];
  }
}

// ---------------------------------------------------------------------------
// GEMM kernels
// ---------------------------------------------------------------------------
// QKV[n][f] = sum_e Xb[n][e] * Wb[f][e] + bc[f]   (bf16 out)
__global__ __launch_bounds__(256) void k_qkv(const unsigned short* __restrict__ Xb,
                                             const unsigned short* __restrict__ Wb,
                                             const float* __restrict__ bc,
                                             unsigned short* __restrict__ QKV) {
  const int m0 = blockIdx.y * 128, n0 = blockIdx.x * 128;
  gemm_bt_core(Xb, Wb, EDIM, EDIM, EDIM, m0, n0,
    [&](f32x4 (&acc)[4][4], int wr, int wc, int lane) {
#pragma unroll
      for (int tm = 0; tm < 4; ++tm)
#pragma unroll
        for (int tn = 0; tn < 4; ++tn) {
          int f = n0 + wc * 64 + tn * 16 + (lane & 15);
          float bias = bc[f];
#pragma unroll
          for (int i = 0; i < 4; ++i) {
            int n = m0 + wr * 64 + tm * 16 + (lane >> 4) * 4 + i;
            QKV[(size_t)n * FQKV + f] = f2bf(acc[tm][tn][i] + bias);
          }
        }
    });
}

// Per batch b (pointers pre-offset): E2[z][q][k] = exp(s * Q_z[q].K_z[k]),
// partial row sums atomically into ls_b + z*NTOK. z = blockIdx.z = which.
__global__ __launch_bounds__(256) void k_scores2(const unsigned short* __restrict__ QKVb,
                                                 unsigned short* __restrict__ E2,
                                                 float* __restrict__ lsb) {
  const int which = blockIdx.z;
  const int m0 = blockIdx.y * 128;  // q tile
  const int n0 = blockIdx.x * 128;  // k tile
  const unsigned short* Aq = QKVb + which * 512;
  const unsigned short* Bk = QKVb + 1024 + which * 512;
  unsigned short* Eb = E2 + (size_t)which * SEQ * SEQ;
  float* lr = lsb + (size_t)which * NTOK;
  gemm_bt_core(Aq, Bk, 512, FQKV, FQKV, m0, n0,
    [&](f32x4 (&acc)[4][4], int wr, int wc, int lane) {
      const float scale = 0.04419417382415922f;  // 1/sqrt(512)
      float rs[4][4];
#pragma unroll
      for (int tm = 0; tm < 4; ++tm)
#pragma unroll
        for (int i = 0; i < 4; ++i) rs[tm][i] = 0.f;
#pragma unroll
      for (int tm = 0; tm < 4; ++tm)
#pragma unroll
        for (int tn = 0; tn < 4; ++tn) {
          int k = n0 + wc * 64 + tn * 16 + (lane & 15);
#pragma unroll
          for (int i = 0; i < 4; ++i) {
            int q = m0 + wr * 64 + tm * 16 + (lane >> 4) * 4 + i;
            float e = __expf(acc[tm][tn][i] * scale);
            unsigned short eb = f2bf(e);
            Eb[(size_t)q * SEQ + k] = eb;
            rs[tm][i] += bf2f(eb);  // sum the rounded value for consistency
          }
        }
#pragma unroll
      for (int tm = 0; tm < 4; ++tm)
#pragma unroll
        for (int i = 0; i < 4; ++i) {
          float v = rs[tm][i];
          v += __shfl_xor(v, 1);
          v += __shfl_xor(v, 2);
          v += __shfl_xor(v, 4);
          v += __shfl_xor(v, 8);
          rs[tm][i] = v;
        }
      if ((lane & 15) == 0) {
#pragma unroll
        for (int tm = 0; tm < 4; ++tm)
#pragma unroll
          for (int i = 0; i < 4; ++i) {
            int q = m0 + wr * 64 + tm * 16 + (lane >> 4) * 4 + i;
            atomicAdd(&lr[q], rs[tm][i]);
          }
      }
    });
}

// Per batch: O12[z][q][d] = sum_k E2[z][q][k] * Vtb[d][k]  (fp32, un-normalized)
__global__ __launch_bounds__(256) void k_pv2(const unsigned short* __restrict__ E2,
                                             const unsigned short* __restrict__ Vtb,
                                             float* __restrict__ O12) {
  const int which = blockIdx.z;
  const int m0 = blockIdx.y * 128;  // q tile
  const int n0 = blockIdx.x * 128;  // d tile
  const unsigned short* Ae = E2 + (size_t)which * SEQ * SEQ;
  float* Ob = O12 + (size_t)which * SEQ * DHEAD;
  gemm_bt_core(Ae, Vtb, SEQ, SEQ, SEQ, m0, n0,
    [&](f32x4 (&acc)[4][4], int wr, int wc, int lane) {
#pragma unroll
      for (int tm = 0; tm < 4; ++tm)
#pragma unroll
        for (int tn = 0; tn < 4; ++tn) {
          int d = n0 + wc * 64 + tn * 16 + (lane & 15);
#pragma unroll
          for (int i = 0; i < 4; ++i) {
            int q = m0 + wr * 64 + tm * 16 + (lane >> 4) * 4 + i;
            Ob[(size_t)q * DHEAD + d] = acc[tm][tn][i];
          }
        }
    });
}

// Per batch: out_b = O1/l1 - lambda * O2/l2
__global__ void k_combine(const float* __restrict__ O12, const float* __restrict__ lsb,
                          const float* __restrict__ lam, float* __restrict__ outb) {
  int i = blockIdx.x * blockDim.x + threadIdx.x;  // per float4, SEQ*DHEAD/4 total
  float lambda = expf(lam[0]) + 0.05f;
  int q = i >> 7;  // 128 float4 per q row
  float inv1 = 1.f / lsb[q];
  float inv2 = lambda / lsb[NTOK + q];
  float4 a = ((const float4*)O12)[i];
  float4 c = ((const float4*)O12)[i + SEQ * DHEAD / 4];
  float4 r;
  r.x = a.x * inv1 - c.x * inv2;
  r.y = a.y * inv1 - c.y * inv2;
  r.z = a.z * inv1 - c.z * inv2;
  r.w = a.w * inv1 - c.w * inv2;
  ((float4*)outb)[i] = r;
}

// ---------------------------------------------------------------------------
extern "C" void kernel_launch(void* const* d_in, const int* in_sizes, int n_in,
                              void* d_out, int out_size, void* d_ws, size_t ws_size,
                              hipStream_t stream) {
  const float* X   = (const float*)d_in[0];
  const float* Wq  = (const float*)d_in[1];
  const float* bq  = (const float*)d_in[2];
  const float* Wk  = (const float*)d_in[3];
  const float* bk  = (const float*)d_in[4];
  const float* Wv  = (const float*)d_in[5];
  const float* bv  = (const float*)d_in[6];
  const float* lam = (const float*)d_in[7];
  float* out = (float*)d_out;

  char* ws = (char*)d_ws;
  size_t off = 0;
  auto alloc = [&](size_t b) { size_t r = off; off += (b + 255) & ~(size_t)255; return r; };
  unsigned short* Xb  = (unsigned short*)(ws + alloc((size_t)NTOK * EDIM * 2));      // 33.6 MB
  unsigned short* Wb  = (unsigned short*)(ws + alloc((size_t)FQKV * EDIM * 2));      // 5.2 MB
  float*          bc  = (float*)(ws + alloc((size_t)FQKV * 4));
  unsigned short* QKV = (unsigned short*)(ws + alloc((size_t)NTOK * FQKV * 2));      // 83.9 MB
  unsigned short* Vt  = (unsigned short*)(ws + alloc((size_t)NB * DHEAD * SEQ * 2)); // 16.8 MB
  unsigned short* E2  = (unsigned short*)(ws + alloc((size_t)2 * SEQ * SEQ * 2));    // 67.1 MB (one batch, both which)
  float*          ls  = (float*)(ws + alloc((size_t)2 * NTOK * 4));                  // 128 KB
  // O12 (one batch, both which, 16.8 MB) aliases Xb — Xb dead after k_qkv.
  float* O12 = (float*)Xb;
  // total ws footprint ~207 MB

  // 1) casts / packing
  k_cvt_x<<<dim3((NTOK * EDIM / 4) / 256), dim3(256), 0, stream>>>(X, Xb);
  k_pack_w<<<dim3((FQKV * EDIM / 4) / 256), dim3(256), 0, stream>>>(Wq, Wk, Wv, Wb);
  k_pack_b<<<dim3(10), dim3(256), 0, stream>>>(bq, bk, bv, bc);
  // 2) QKV projection
  k_qkv<<<dim3(FQKV / 128, NTOK / 128), dim3(256), 0, stream>>>(Xb, Wb, bc, QKV);
  // 3) V transpose
  k_trv<<<dim3(SEQ / 32, DHEAD / 32, NB), dim3(32, 8), 0, stream>>>(QKV, Vt);
  // 4) zero row-sum accumulators (re-poisoned to 0xAA before every timed call)
  k_zero_f<<<dim3(2 * NTOK / 256), dim3(256), 0, stream>>>(ls);
  // 5) per-batch attention: scores+exp -> PV -> combine (E2/O12 reused)
  for (int b = 0; b < NB; ++b) {
    const unsigned short* QKVb = QKV + (size_t)b * SEQ * FQKV;
    const unsigned short* Vtb  = Vt + (size_t)b * DHEAD * SEQ;
    float* lsb  = ls + (size_t)b * SEQ;
    float* outb = out + (size_t)b * SEQ * DHEAD;
    k_scores2<<<dim3(SEQ / 128, SEQ / 128, 2), dim3(256), 0, stream>>>(QKVb, E2, lsb);
    k_pv2<<<dim3(DHEAD / 128, SEQ / 128, 2), dim3(256), 0, stream>>>(E2, Vtb, O12);
    k_combine<<<dim3((SEQ * DHEAD / 4) / 256), dim3(256), 0, stream>>>(O12, lsb, lam, outb);
  }

  (void)in_sizes; (void)n_in; (void)out_size; (void)ws_size;
}

// Round 3
// 879.185 us; speedup vs baseline: 1.0528x; 1.0528x over previous
//
#include <hip/hip_runtime.h>
#include <cstdint>
#include <cstddef>

// Problem constants
#define NB    4
#define SEQ   4096
#define EDIM  1024
#define DHEAD 512
#define NTOK  (NB * SEQ)     // 16384
#define FQK   2048           // Q and K features only
#define FQKV  2560

typedef __bf16 bf16x8 __attribute__((ext_vector_type(8)));
typedef float  f32x4  __attribute__((ext_vector_type(4)));

__device__ __forceinline__ unsigned short f2bf(float f) {
  union { float f; unsigned int u; } v; v.f = f;
  return (unsigned short)((v.u + 0x7fffu + ((v.u >> 16) & 1u)) >> 16);
}
__device__ __forceinline__ float bf2f(unsigned short h) {
  union { unsigned int u; float f; } v; v.u = ((unsigned int)h) << 16;
  return v.f;
}

// async global->LDS, 16B per lane; LDS dest wave-uniform base, lane i -> base+i*16.
__device__ __forceinline__ void gld_lds16(const void* g, void* l) {
  __builtin_amdgcn_global_load_lds(
      (const __attribute__((address_space(1))) unsigned int*)g,
      (__attribute__((address_space(3))) unsigned int*)l, 16, 0, 0);
}

// ---------------------------------------------------------------------------
// m97-style GEMM-BT core: C(128x128) = A(128xK) * B(128xK)^T, bf16 in, fp32 acc.
// A rows m0..m0+127 (lda), B rows n0..n0+127 (ldb). 256 thr = 4 waves 2x2.
// epi(acc, wr, wc, lane): C[m][n], m = m0+wr*64+tm*16+(lane>>4)*4+i,
// n = n0+wc*64+tn*16+(lane&15).
// ---------------------------------------------------------------------------
template <class Epi>
__device__ __forceinline__ void gemm_bt_core(
    const unsigned short* __restrict__ A, const unsigned short* __restrict__ B,
    int K, int lda, int ldb, int m0, int n0, Epi epi) {
  __shared__ __align__(16) unsigned short As[128 * 32];
  __shared__ __align__(16) unsigned short Bs[128 * 32];
  const int t = threadIdx.x;
  const int w = t >> 6;
  const int lane = t & 63;
  const int wr = w >> 1, wc = w & 1;

  f32x4 acc[4][4];
#pragma unroll
  for (int i = 0; i < 4; ++i)
#pragma unroll
    for (int j = 0; j < 4; ++j) acc[i][j] = f32x4{0.f, 0.f, 0.f, 0.f};

  // Staging: tile 128x32 bf16 = 8KB = 512 x 16B chunks; chunk c: row=c>>2,
  // col8=(c&3)*8. Wave w covers chunks [w*128, w*128+128) via 2 gld16.
  const int c0 = (w * 2) * 64 + lane;
  const int c1 = (w * 2 + 1) * 64 + lane;
  const int r0 = c0 >> 2, col0 = (c0 & 3) * 8;
  const int r1 = c1 >> 2, col1 = (c1 & 3) * 8;
  unsigned short* ldsA0 = &As[(w * 2) * 512];       // wave-uniform
  unsigned short* ldsA1 = &As[(w * 2 + 1) * 512];
  unsigned short* ldsB0 = &Bs[(w * 2) * 512];
  unsigned short* ldsB1 = &Bs[(w * 2 + 1) * 512];
  const unsigned short* gA0 = A + (size_t)(m0 + r0) * lda + col0;
  const unsigned short* gA1 = A + (size_t)(m0 + r1) * lda + col1;
  const unsigned short* gB0 = B + (size_t)(n0 + r0) * ldb + col0;
  const unsigned short* gB1 = B + (size_t)(n0 + r1) * ldb + col1;

  for (int kt = 0; kt < K; kt += 32) {
    gld_lds16(gA0 + kt, ldsA0);
    gld_lds16(gA1 + kt, ldsA1);
    gld_lds16(gB0 + kt, ldsB0);
    gld_lds16(gB1 + kt, ldsB1);
    __syncthreads();  // compiler drains vmcnt before barrier -> staging visible

    bf16x8 af[4], bfr[4];
#pragma unroll
    for (int tm = 0; tm < 4; ++tm) {
      int r = wr * 64 + tm * 16 + (lane & 15);
      af[tm] = *(const bf16x8*)&As[r * 32 + (lane >> 4) * 8];
    }
#pragma unroll
    for (int tn = 0; tn < 4; ++tn) {
      int r = wc * 64 + tn * 16 + (lane & 15);
      bfr[tn] = *(const bf16x8*)&Bs[r * 32 + (lane >> 4) * 8];
    }
#pragma unroll
    for (int tm = 0; tm < 4; ++tm)
#pragma unroll
      for (int tn = 0; tn < 4; ++tn)
        acc[tm][tn] = __builtin_amdgcn_mfma_f32_16x16x32_bf16(
            af[tm], bfr[tn], acc[tm][tn], 0, 0, 0);
    __syncthreads();
  }
  epi(acc, wr, wc, lane);
}

// ---------------------------------------------------------------------------
// Utility kernels
// ---------------------------------------------------------------------------
__global__ void k_cvt_x(const float* __restrict__ X, unsigned short* __restrict__ Xb) {
  int i = blockIdx.x * blockDim.x + threadIdx.x;  // per float4, exact grid
  float4 v = ((const float4*)X)[i];
  ushort4 o;
  o.x = f2bf(v.x); o.y = f2bf(v.y); o.z = f2bf(v.z); o.w = f2bf(v.w);
  ((ushort4*)Xb)[i] = o;
}

// Wb rows: 0..1023 = Wq, 1024..2047 = Wk, 2048..2559 = Wv
__global__ void k_pack_w(const float* __restrict__ Wq, const float* __restrict__ Wk,
                         const float* __restrict__ Wv, unsigned short* __restrict__ Wb) {
  int i = blockIdx.x * blockDim.x + threadIdx.x;  // per 4 elems
  int idx = i * 4;
  int f = idx >> 10, e = idx & 1023;
  const float* src = (f < 1024) ? (Wq + (size_t)f * 1024)
                   : (f < 2048) ? (Wk + (size_t)(f - 1024) * 1024)
                                : (Wv + (size_t)(f - 2048) * 1024);
  float4 v = *(const float4*)(src + e);
  ushort4 o;
  o.x = f2bf(v.x); o.y = f2bf(v.y); o.z = f2bf(v.z); o.w = f2bf(v.w);
  ((ushort4*)Wb)[i] = o;
}

__global__ void k_pack_b(const float* __restrict__ bq, const float* __restrict__ bk,
                         const float* __restrict__ bv, float* __restrict__ bc) {
  int f = blockIdx.x * blockDim.x + threadIdx.x;  // 2560 total
  if (f < FQKV)
    bc[f] = (f < 1024) ? bq[f] : (f < 2048) ? bk[f - 1024] : bv[f - 2048];
}

__global__ void k_zero_f(float* __restrict__ p) {
  int i = blockIdx.x * blockDim.x + threadIdx.x;
  p[i] = 0.f;
}

// ---------------------------------------------------------------------------
// GEMM kernels
// ---------------------------------------------------------------------------
// QK[n][f] = sum_e Xb[n][e]*Wb[f][e] + bc[f], f in [0,2048)   (bf16 out)
__global__ __launch_bounds__(256) void k_qk(const unsigned short* __restrict__ Xb,
                                            const unsigned short* __restrict__ Wb,
                                            const float* __restrict__ bc,
                                            unsigned short* __restrict__ QK) {
  const int m0 = blockIdx.y * 128, n0 = blockIdx.x * 128;
  gemm_bt_core(Xb, Wb, EDIM, EDIM, EDIM, m0, n0,
    [&](f32x4 (&acc)[4][4], int wr, int wc, int lane) {
#pragma unroll
      for (int tm = 0; tm < 4; ++tm)
#pragma unroll
        for (int tn = 0; tn < 4; ++tn) {
          int f = n0 + wc * 64 + tn * 16 + (lane & 15);
          float bias = bc[f];
#pragma unroll
          for (int i = 0; i < 4; ++i) {
            int n = m0 + wr * 64 + tm * 16 + (lane >> 4) * 4 + i;
            QK[(size_t)n * FQK + f] = f2bf(acc[tm][tn][i] + bias);
          }
        }
    });
}

// Vt[b][d][s] = sum_e Wv[d][e]*Xb[b*SEQ+s][e] + bv[d]   (bf16, transposed V)
// A = Wv rows (m = d), B = X rows of batch b (n = s). Grid (s-tiles, d-tiles, b).
__global__ __launch_bounds__(256) void k_v(const unsigned short* __restrict__ Xb,
                                           const unsigned short* __restrict__ Wb,
                                           const float* __restrict__ bc,
                                           unsigned short* __restrict__ Vt) {
  const int b = blockIdx.z;
  const int m0 = blockIdx.y * 128;  // d tile
  const int n0 = blockIdx.x * 128;  // s tile
  const unsigned short* A = Wb + (size_t)2048 * EDIM;
  const unsigned short* B = Xb + (size_t)b * SEQ * EDIM;
  unsigned short* Vb = Vt + (size_t)b * DHEAD * SEQ;
  gemm_bt_core(A, B, EDIM, EDIM, EDIM, m0, n0,
    [&](f32x4 (&acc)[4][4], int wr, int wc, int lane) {
#pragma unroll
      for (int tm = 0; tm < 4; ++tm)
#pragma unroll
        for (int tn = 0; tn < 4; ++tn) {
          int s = n0 + wc * 64 + tn * 16 + (lane & 15);
#pragma unroll
          for (int i = 0; i < 4; ++i) {
            int d = m0 + wr * 64 + tm * 16 + (lane >> 4) * 4 + i;
            Vb[(size_t)d * SEQ + s] = f2bf(acc[tm][tn][i] + bc[2048 + d]);
          }
        }
    });
}

// Chunk of 2 batches, both which: z -> (rb = z>>1, which = z&1), batch = b0+rb.
// E_c[z][q][k] = exp(s * Q.K); partial row sums atomically into ls[which][b][q].
__global__ __launch_bounds__(256) void k_scores2(const unsigned short* __restrict__ QK,
                                                 unsigned short* __restrict__ E_c,
                                                 float* __restrict__ ls, int b0) {
  const int z = blockIdx.z;
  const int rb = z >> 1, which = z & 1;
  const int b = b0 + rb;
  const int m0 = blockIdx.y * 128;  // q tile
  const int n0 = blockIdx.x * 128;  // k tile
  const unsigned short* Aq = QK + (size_t)b * SEQ * FQK + which * 512;
  const unsigned short* Bk = QK + (size_t)b * SEQ * FQK + 1024 + which * 512;
  unsigned short* Eb = E_c + (size_t)z * SEQ * SEQ;
  float* lr = ls + (size_t)which * NTOK + (size_t)b * SEQ;
  gemm_bt_core(Aq, Bk, 512, FQK, FQK, m0, n0,
    [&](f32x4 (&acc)[4][4], int wr, int wc, int lane) {
      const float scale = 0.04419417382415922f;  // 1/sqrt(512)
      float rs[4][4];
#pragma unroll
      for (int tm = 0; tm < 4; ++tm)
#pragma unroll
        for (int i = 0; i < 4; ++i) rs[tm][i] = 0.f;
#pragma unroll
      for (int tm = 0; tm < 4; ++tm)
#pragma unroll
        for (int tn = 0; tn < 4; ++tn) {
          int k = n0 + wc * 64 + tn * 16 + (lane & 15);
#pragma unroll
          for (int i = 0; i < 4; ++i) {
            int q = m0 + wr * 64 + tm * 16 + (lane >> 4) * 4 + i;
            float e = __expf(acc[tm][tn][i] * scale);
            unsigned short eb = f2bf(e);
            Eb[(size_t)q * SEQ + k] = eb;
            rs[tm][i] += bf2f(eb);  // sum rounded value for consistency
          }
        }
#pragma unroll
      for (int tm = 0; tm < 4; ++tm)
#pragma unroll
        for (int i = 0; i < 4; ++i) {
          float v = rs[tm][i];
          v += __shfl_xor(v, 1);
          v += __shfl_xor(v, 2);
          v += __shfl_xor(v, 4);
          v += __shfl_xor(v, 8);
          rs[tm][i] = v;
        }
      if ((lane & 15) == 0) {
#pragma unroll
        for (int tm = 0; tm < 4; ++tm)
#pragma unroll
          for (int i = 0; i < 4; ++i) {
            int q = m0 + wr * 64 + tm * 16 + (lane >> 4) * 4 + i;
            atomicAdd(&lr[q], rs[tm][i]);
          }
      }
    });
}

// O12[z][q][d] = sum_k E_c[z][q][k] * Vt[b0+ (z>>1)][d][k]  (fp32, un-normalized)
__global__ __launch_bounds__(256) void k_pv2(const unsigned short* __restrict__ E_c,
                                             const unsigned short* __restrict__ Vt,
                                             float* __restrict__ O12, int b0) {
  const int z = blockIdx.z;
  const int b = b0 + (z >> 1);
  const int m0 = blockIdx.y * 128;  // q tile
  const int n0 = blockIdx.x * 128;  // d tile
  const unsigned short* Ae = E_c + (size_t)z * SEQ * SEQ;
  const unsigned short* Bv = Vt + (size_t)b * DHEAD * SEQ;
  float* Ob = O12 + (size_t)z * SEQ * DHEAD;
  gemm_bt_core(Ae, Bv, SEQ, SEQ, SEQ, m0, n0,
    [&](f32x4 (&acc)[4][4], int wr, int wc, int lane) {
#pragma unroll
      for (int tm = 0; tm < 4; ++tm)
#pragma unroll
        for (int tn = 0; tn < 4; ++tn) {
          int d = n0 + wc * 64 + tn * 16 + (lane & 15);
#pragma unroll
          for (int i = 0; i < 4; ++i) {
            int q = m0 + wr * 64 + tm * 16 + (lane >> 4) * 4 + i;
            Ob[(size_t)q * DHEAD + d] = acc[tm][tn][i];
          }
        }
    });
}

// Chunk combine: out[b0+rb] = O12[rb*2+0]/l1 - lambda * O12[rb*2+1]/l2
__global__ void k_combine(const float* __restrict__ O12, const float* __restrict__ ls,
                          const float* __restrict__ lam, float* __restrict__ out, int b0) {
  int i = blockIdx.x * blockDim.x + threadIdx.x;  // per float4, 2*SEQ*DHEAD/4
  float lambda = expf(lam[0]) + 0.05f;
  int gq = i >> 7;            // 128 float4 per row
  int rb = gq >> 12;          // 4096 rows per batch
  int q = gq & 4095;
  int dv = i & 127;
  int b = b0 + rb;
  float inv1 = 1.f / ls[(size_t)b * SEQ + q];
  float inv2 = lambda / ls[NTOK + (size_t)b * SEQ + q];
  size_t ai = (size_t)(rb * 2) * (SEQ * 128) + (size_t)q * 128 + dv;
  float4 a = ((const float4*)O12)[ai];
  float4 c = ((const float4*)O12)[ai + SEQ * 128];
  float4 r;
  r.x = a.x * inv1 - c.x * inv2;
  r.y = a.y * inv1 - c.y * inv2;
  r.z = a.z * inv1 - c.z * inv2;
  r.w = a.w * inv1 - c.w * inv2;
  ((float4*)out)[(size_t)(b * SEQ + q) * 128 + dv] = r;
}

// ---------------------------------------------------------------------------
extern "C" void kernel_launch(void* const* d_in, const int* in_sizes, int n_in,
                              void* d_out, int out_size, void* d_ws, size_t ws_size,
                              hipStream_t stream) {
  const float* X   = (const float*)d_in[0];
  const float* Wq  = (const float*)d_in[1];
  const float* bq  = (const float*)d_in[2];
  const float* Wk  = (const float*)d_in[3];
  const float* bk  = (const float*)d_in[4];
  const float* Wv  = (const float*)d_in[5];
  const float* bv  = (const float*)d_in[6];
  const float* lam = (const float*)d_in[7];
  float* out = (float*)d_out;

  char* ws = (char*)d_ws;
  size_t off = 0;
  auto alloc = [&](size_t b) { size_t r = off; off += (b + 255) & ~(size_t)255; return r; };
  unsigned short* Xb  = (unsigned short*)(ws + alloc((size_t)NTOK * EDIM * 2));    // 32 MiB
  unsigned short* Wb  = (unsigned short*)(ws + alloc((size_t)FQKV * EDIM * 2));    // 5 MiB
  float*          bc  = (float*)(ws + alloc((size_t)FQKV * 4));
  unsigned short* QK  = (unsigned short*)(ws + alloc((size_t)NTOK * FQK * 2));     // 64 MiB
  unsigned short* Vt  = (unsigned short*)(ws + alloc((size_t)NB * DHEAD * SEQ * 2)); // 16 MiB
  unsigned short* E_c = (unsigned short*)(ws + alloc((size_t)4 * SEQ * SEQ * 2));  // 128 MiB (2 batches x 2 which)
  float*          ls  = (float*)(ws + alloc((size_t)2 * NTOK * 4));                // 128 KiB
  // O12 (2 batches x 2 which x SEQ x DHEAD fp32 = 32 MiB) aliases Xb — Xb dead
  // after k_v; first pv write is stream-after k_v.
  float* O12 = (float*)Xb;
  // total ws ~245.2 MiB (< 256 MiB)

  // 1) casts / packing
  k_cvt_x<<<dim3((NTOK * EDIM / 4) / 256), dim3(256), 0, stream>>>(X, Xb);
  k_pack_w<<<dim3((FQKV * EDIM / 4) / 256), dim3(256), 0, stream>>>(Wq, Wk, Wv, Wb);
  k_pack_b<<<dim3(10), dim3(256), 0, stream>>>(bq, bk, bv, bc);
  // 2) QK projection (2048 blocks) and direct V^T projection (512 blocks)
  k_qk<<<dim3(FQK / 128, NTOK / 128), dim3(256), 0, stream>>>(Xb, Wb, bc, QK);
  k_v<<<dim3(SEQ / 128, DHEAD / 128, NB), dim3(256), 0, stream>>>(Xb, Wb, bc, Vt);
  // 3) zero row-sum accumulators
  k_zero_f<<<dim3(2 * NTOK / 256), dim3(256), 0, stream>>>(ls);
  // 4) attention in 2 chunks of 2 batches (both which per chunk)
  for (int b0 = 0; b0 < NB; b0 += 2) {
    k_scores2<<<dim3(SEQ / 128, SEQ / 128, 4), dim3(256), 0, stream>>>(QK, E_c, ls, b0);
    k_pv2<<<dim3(DHEAD / 128, SEQ / 128, 4), dim3(256), 0, stream>>>(E_c, Vt, O12, b0);
    k_combine<<<dim3((2 * SEQ * DHEAD / 4) / 256), dim3(256), 0, stream>>>(O12, ls, lam, out, b0);
  }

  (void)in_sizes; (void)n_in; (void)out_size; (void)ws_size;
}